// Round 10
// baseline (290.303 us; speedup 1.0000x reference)
//
#include <hip/hip_runtime.h>

typedef unsigned short u16;
typedef __attribute__((ext_vector_type(8))) _Float16 f16x8;
typedef __attribute__((ext_vector_type(4))) float f32x4;
typedef __attribute__((ext_vector_type(4))) unsigned short u16x4;
typedef __attribute__((ext_vector_type(8))) unsigned short u16x8;

#define MFMA16F __builtin_amdgcn_mfma_f32_16x16x32_f16

#define HW   16384
#define NCLS 150
#define NPAD 160
#define CDIM 256

// LDS strides (shorts)
#define FT_STRIDE 264   // featT [64 px][256 c]
#define FN_STRIDE 72    // featN [256 c][64 px]
#define EP_STRIDE 72    // E'    [160 n][64 px]
#define W_STRIDE  168   // E/clsWT [.][160 n]
#define CL_STRIDE 264   // cls   [80 n][256 c]
#define CT_STRIDE 264   // combT tile [80 n][256 k]

// kS3 LDS (bytes): 76 KB -> 2 blocks/CU
#define S3_CLS  0        // [80][264] u16 = 42240
#define S3_FT   42240    // [64][264] u16 = 33792
#define S3_ROWM 76032    // [80][4] f32 = 1280
#define S3_ROWS 77312    // [80][4] f32 = 1280
#define S3_MRUN 78592    // [80] f32 = 320
#define S3_LRUN 78912    // [80] f32 = 320
#define S3_LDS  79232

// kOut1 LDS (bytes)
#define O1_CLS  0        // [256][168] u16 = 86016
#define O1_E    86016    // [64][168] u16 = 21504 (raw S^T, then exp values)
#define O1_MP   107520   // [64] f32
#define O1_PS   107776   // [64][8] f32 = 2048
#define O1_RZ   109824   // [64] f32
#define O1_LDS  110080

// workspace offsets (bytes) — same map as r9 (mp/rzp regions now unused)
#define WS_CLSF  0          // [8][160][256] f16
#define WS_CLSWT 655360     // [8][256][160] f16
#define WS_MG    2359296    // [8][160] f32
#define WS_RZ    2364416    // [8][160] f32
#define WS_WCF   2369536    // [256][256] f16
#define WS_COMBT 2500608    // [8][160][256] f16
#define WS_ROWP  3155968    // [8][32][160][2] f32 (part aliases after kComb)
#define WS_PART  3155968    // [8][32][256][160] f16 (written later by kOut0)
#define WS_S     24127488   // [8][160][16384] f16

__device__ __forceinline__ u16 f2h(float f){ return __builtin_bit_cast(u16, (_Float16)f); }
__device__ __forceinline__ float h2f(u16 h){ return (float)__builtin_bit_cast(_Float16, h); }

// ---------------- k0: cls -> f16 (padded 160 rows, pads zero), clsWT = (cls @ Wf^T)^T f16
__global__ __launch_bounds__(256) void k0(const float* __restrict__ cls, const float* __restrict__ Wf,
                                          u16* __restrict__ clsF, u16* __restrict__ clsWT){
  int b = blockIdx.x / NPAD, n = blockIdx.x % NPAD, t = threadIdx.x;
  __shared__ float row[256];
  int bn = b*NPAD + n;
  if (n < NCLS){
    float v = cls[(b*NCLS + n)*CDIM + t];
    clsF[bn*CDIM + t] = f2h(v);
    row[t] = v;
    __syncthreads();
    float acc = 0.f;
    const float* wr = Wf + t*CDIM;
    #pragma unroll 4
    for (int c = 0; c < 256; c += 4){
      acc += row[c]*wr[c] + row[c+1]*wr[c+1] + row[c+2]*wr[c+2] + row[c+3]*wr[c+3];
    }
    clsWT[(b*CDIM + t)*NPAD + n] = f2h(acc);
  } else {
    clsF[bn*CDIM + t] = 0;
    clsWT[(b*CDIM + t)*NPAD + n] = 0;
  }
}

// ---------------- kW: Wc f32 -> f16
__global__ __launch_bounds__(512) void kW(const float* __restrict__ Wc, u16* __restrict__ WcF){
  int i = (blockIdx.x*512 + threadIdx.x)*4;
  f32x4 v = *(const f32x4*)&Wc[i];
  u16x4 o = {f2h(v[0]), f2h(v[1]), f2h(v[2]), f2h(v[3])};
  *(u16x4*)&WcF[i] = o;
}

// ---------------- kS3: S GEMM (n split in halves -> 2 blocks/CU) + shfl row-stats only.
// Pixel (pos) stats moved to kOut1 (axis is tile-local there) — removes r9's serial column scan.
__global__ __launch_bounds__(256) void kS3(const float* __restrict__ feat, const u16* __restrict__ clsF,
                                           u16* __restrict__ Sg, float* __restrict__ rowP){
  extern __shared__ char sm[];
  u16*  clsL = (u16*)(sm + S3_CLS);
  u16*  ftF  = (u16*)(sm + S3_FT);
  float* rowM = (float*)(sm + S3_ROWM);
  float* rowS = (float*)(sm + S3_ROWS);
  float* mrun = (float*)(sm + S3_MRUN);
  float* lrun = (float*)(sm + S3_LRUN);
  int bid = blockIdx.x;
  int b = bid & 7, nh = (bid >> 3) & 1, ch = bid >> 4;   // ch 0..31
  int t = threadIdx.x;
  const u16* clsB = clsF + (b*NPAD + nh*80)*CDIM;
  const float* featG = feat + (size_t)b*CDIM*HW;
  u16* Sb = Sg + (size_t)b*NPAD*HW + (size_t)(nh*80)*HW;
  // stage cls half [80][256] -> LDS [80][264] (once)
  #pragma unroll
  for (int it = 0; it < 10; ++it){
    int idx8 = (it*256 + t)*8;          // 20480 shorts exactly
    int r = idx8 >> 8, c = idx8 & 255;
    u16x8 v = *(const u16x8*)&clsB[idx8];
    *(u16x8*)&clsL[r*CL_STRIDE + c] = v;
  }
  int lane = t & 63, wv = t >> 6;       // 4 waves
  int l15 = lane & 15, lk = (lane >> 4) & 3;
  int pq = wv;                          // col quad
  int col = pq*16 + l15;
  if (t < 80){ mrun[t] = -3.0e38f; lrun[t] = 0.f; }
  __syncthreads();

  for (int sub = 0; sub < 8; ++sub){
    int p0 = ch*512 + sub*64;
    // ---- stage feat [256c x 64px] f32 -> f16 LDS [px][c]
    {
      int p = t & 63, cg = t >> 6;      // cg 0..3
      #pragma unroll
      for (int i = 0; i < 16; ++i){
        int c0 = (i*4 + cg)*4;
        const float* g0 = featG + (size_t)c0*HW + p0 + p;
        float v0 = g0[0], v1 = g0[HW], v2 = g0[2*HW], v3 = g0[3*HW];
        u16x4 hv = {f2h(v0), f2h(v1), f2h(v2), f2h(v3)};
        *(u16x4*)&ftF[p*FT_STRIDE + c0] = hv;
      }
    }
    __syncthreads();   // B1
    // ---- GEMM: 5 row-frags x this wave's col quad, all-LDS operands
    f32x4 acc[5];
    #pragma unroll
    for (int f = 0; f < 5; ++f) acc[f] = (f32x4){0.f,0.f,0.f,0.f};
    #pragma unroll
    for (int kb = 0; kb < 8; ++kb){
      int ko = kb*32 + lk*8;
      f16x8 bh = *(const f16x8*)&ftF[(pq*16 + l15)*FT_STRIDE + ko];
      #pragma unroll
      for (int f = 0; f < 5; ++f){
        f16x8 ah = *(const f16x8*)&clsL[(f*16 + l15)*CL_STRIDE + ko];
        acc[f] = MFMA16F(ah, bh, acc[f], 0, 0, 0);
      }
    }
    // ---- write S (local rows 0..79)
    #pragma unroll
    for (int f = 0; f < 5; ++f){
      #pragma unroll
      for (int r = 0; r < 4; ++r){
        int n = f*16 + 4*lk + r;
        Sb[(size_t)n*HW + p0 + col] = f2h(acc[f][r]);
      }
    }
    // ---- row stats: shfl-reduce (m,s) over this wave's 16 cols
    #pragma unroll
    for (int f = 0; f < 5; ++f){
      #pragma unroll
      for (int r = 0; r < 4; ++r){
        float v = acc[f][r];
        float m = v;
        m = fmaxf(m, __shfl_xor(m, 1));
        m = fmaxf(m, __shfl_xor(m, 2));
        m = fmaxf(m, __shfl_xor(m, 4));
        m = fmaxf(m, __shfl_xor(m, 8));
        float s = __expf(v - m);
        s += __shfl_xor(s, 1);
        s += __shfl_xor(s, 2);
        s += __shfl_xor(s, 4);
        s += __shfl_xor(s, 8);
        if (l15 == f){
          int n = f*16 + 4*lk + r;
          rowM[n*4 + pq] = m;
          rowS[n*4 + pq] = s;
        }
      }
    }
    __syncthreads();   // B2
    // ---- combine 4 pq partials into running (m,l)
    if (t < 80){
      float rm0 = rowM[t*4+0], rm1 = rowM[t*4+1], rm2 = rowM[t*4+2], rm3 = rowM[t*4+3];
      float msub = fmaxf(fmaxf(rm0, rm1), fmaxf(rm2, rm3));
      float l = rowS[t*4+0]*__expf(rm0 - msub) + rowS[t*4+1]*__expf(rm1 - msub)
              + rowS[t*4+2]*__expf(rm2 - msub) + rowS[t*4+3]*__expf(rm3 - msub);
      float m2 = fmaxf(mrun[t], msub);
      lrun[t] = lrun[t]*__expf(mrun[t] - m2) + l*__expf(msub - m2);
      mrun[t] = m2;
    }
  }
  if (t < 80){
    float* rp = rowP + ((size_t)(b*32 + ch)*NPAD + nh*80 + t)*2;
    rp[0] = mrun[t];
    rp[1] = lrun[t];
  }
}

// ---------------- kComb: reduce 32 chunk row-partials -> m_g, rZ
__global__ __launch_bounds__(256) void kComb(const float* __restrict__ rowP,
                                             float* __restrict__ mg, float* __restrict__ rz){
  int b = blockIdx.x, t = threadIdx.x;
  if (t < NPAD){
    float m = -3.0e38f, l = 0.f;
    for (int s = 0; s < 32; ++s){
      const float* rp = rowP + ((size_t)(b*32 + s)*NPAD + t)*2;
      float ms = rp[0], ls = rp[1];
      float mn = fmaxf(m, ms);
      l = l*__expf(m - mn) + ls*__expf(ms - mn);
      m = mn;
    }
    mg[b*NPAD + t] = m;
    rz[b*NPAD + t] = 1.0f / l;
  }
}

// ---------------- kOut1 v3: local pixel softmax (full n range is tile-local) + GEMM
__global__ __launch_bounds__(512) void kOut1(const u16* __restrict__ Sg, const u16* __restrict__ clsWT,
                                             const float* __restrict__ feat, float* __restrict__ out1){
  extern __shared__ char sm[];
  u16*  A    = (u16*)(sm + O1_CLS);   // [256 c][168 n]
  u16*  E    = (u16*)(sm + O1_E);     // [64 px][168 n]
  float* mpL  = (float*)(sm + O1_MP);
  float* psum = (float*)(sm + O1_PS);
  float* rzL  = (float*)(sm + O1_RZ);
  int b = blockIdx.x & 7, ch = blockIdx.x >> 3, t = threadIdx.x;
  const u16* Sb = Sg + (size_t)b*NPAD*HW;
  const u16* clsWB = clsWT + b*CDIM*NPAD;
  const float* featB = feat + (size_t)b*CDIM*HW;
  // stage clsWT [256][160] -> LDS [256][168] (once)
  #pragma unroll
  for (int it = 0; it < 10; ++it){
    int idx8 = (it*512 + t)*8;
    int c = idx8 / NPAD, n = idx8 % NPAD;
    u16x8 v = *(const u16x8*)&clsWB[idx8];
    *(u16x8*)&A[c*W_STRIDE + n] = v;
  }
  int lane = t & 63, wv = t >> 6;
  int l15 = lane & 15, lk = (lane >> 4) & 3;
  int cstrip = wv*32;
  int rr = t >> 3, px8v = (t & 7)*8;
  __syncthreads();

  for (int sub = 0; sub < 8; ++sub){
    int p0 = ch*512 + sub*64;
    // ---- P1: stage RAW S^T (rows < 150 only; pads handled in P3)
    #pragma unroll
    for (int ps = 0; ps < 3; ++ps){
      int rowi = ps*64 + rr;
      if (rowi < NCLS){
        u16x8 v = *(const u16x8*)&Sb[(size_t)rowi*HW + p0 + px8v];
        #pragma unroll
        for (int j = 0; j < 8; ++j) E[(px8v + j)*W_STRIDE + rowi] = v[j];
      }
    }
    __syncthreads();   // B1
    // ---- P2: per-pixel max (contiguous row scan, n<150)
    if (t < 64){
      float mt = -3.0e38f;
      #pragma unroll
      for (int q = 0; q < 18; ++q){
        u16x8 v = *(const u16x8*)&E[t*W_STRIDE + q*8];
        #pragma unroll
        for (int j = 0; j < 8; ++j) mt = fmaxf(mt, h2f(v[j]));
      }
      for (int n = 144; n < NCLS; ++n) mt = fmaxf(mt, h2f(E[t*W_STRIDE + n]));
      mpL[t] = mt;
    }
    __syncthreads();   // B2
    // ---- P3: convert raw->exp in place (all 512 threads), partial sums; zero pads
    {
      int px = t >> 3, sl = t & 7;
      float mt = mpL[px];
      float s = 0.f;
      int n0 = sl*21;
      for (int n = n0; n < n0 + 21; ++n){
        float e = 0.f;
        if (n < NCLS){ e = __expf(h2f(E[px*W_STRIDE + n]) - mt); s += e; }
        if (n < NPAD) E[px*W_STRIDE + n] = f2h(e);
      }
      psum[px*8 + sl] = s;
    }
    __syncthreads();   // B3
    // ---- P4: rz (t<64) concurrent with GEMM
    if (t < 64){
      float z = 0.f;
      #pragma unroll
      for (int j = 0; j < 8; ++j) z += psum[t*8 + j];
      rzL[t] = 1.0f / z;
    }
    f32x4 acc[2][4];
    #pragma unroll
    for (int cf = 0; cf < 2; ++cf)
      #pragma unroll
      for (int pf = 0; pf < 4; ++pf) acc[cf][pf] = (f32x4){0.f,0.f,0.f,0.f};
    #pragma unroll
    for (int kb = 0; kb < 5; ++kb){
      int ko = kb*32 + lk*8;
      f16x8 a0 = *(const f16x8*)&A[(cstrip + l15)*W_STRIDE + ko];
      f16x8 a1 = *(const f16x8*)&A[(cstrip + 16 + l15)*W_STRIDE + ko];
      #pragma unroll
      for (int pf = 0; pf < 4; ++pf){
        f16x8 bb = *(const f16x8*)&E[(pf*16 + l15)*W_STRIDE + ko];
        acc[0][pf] = MFMA16F(a0, bb, acc[0][pf], 0, 0, 0);
        acc[1][pf] = MFMA16F(a1, bb, acc[1][pf], 0, 0, 0);
      }
    }
    __syncthreads();   // B4: rzL visible; E reads done
    // ---- epilogue: scale by 1/Z, add feat residual
    #pragma unroll
    for (int cf = 0; cf < 2; ++cf){
      #pragma unroll
      for (int r = 0; r < 4; ++r){
        int c = cstrip + cf*16 + lk*4 + r;
        const float* fr = featB + (size_t)c*HW + p0;
        float* ob = out1 + (size_t)(b*CDIM + c)*HW + p0;
        #pragma unroll
        for (int pf = 0; pf < 4; ++pf){
          int pp = pf*16 + l15;
          ob[pp] = acc[cf][pf][r]*rzL[pp] + fr[pp];
        }
      }
    }
  }
}

// ---------------- kOut0: part[c][n] = sum_p featF16[c][p] * exp(S - m_g[n])  (512 px/block)
__global__ __launch_bounds__(512) void kOut0(const u16* __restrict__ Sg, const float* __restrict__ feat,
                                             const float* __restrict__ mg, u16* __restrict__ part){
  extern __shared__ char sm[];
  u16* Ep = (u16*)sm;                        // [NPAD][EP_STRIDE]
  u16* fN = (u16*)(sm + NPAD*EP_STRIDE*2);   // [CDIM][FN_STRIDE]
  int b = blockIdx.x & 7, pr = blockIdx.x >> 3, t = threadIdx.x;
  const u16* Sb = Sg + (size_t)b*NPAD*HW;
  const float* featB = feat + (size_t)b*CDIM*HW;
  const float* mgB = mg + b*NPAD;
  int lane = t & 63, wv = t >> 6;
  int l15 = lane & 15, lk = (lane >> 4) & 3;
  int cstrip = wv*32;
  int rr = t >> 3, px8 = (t & 7)*8;
  f32x4 acc[2][10];
  #pragma unroll
  for (int cf = 0; cf < 2; ++cf)
    #pragma unroll
    for (int nf = 0; nf < 10; ++nf) acc[cf][nf] = (f32x4){0.f,0.f,0.f,0.f};
  for (int ck = 0; ck < 8; ++ck){
    int p0 = pr*512 + ck*64;
    #pragma unroll
    for (int ps = 0; ps < 3; ++ps){
      int rowi = ps*64 + rr;
      if (rowi < NPAD){
        u16x8 v = *(const u16x8*)&Sb[(size_t)rowi*HW + p0 + px8];
        float m = mgB[rowi];
        u16x8 o;
        #pragma unroll
        for (int j = 0; j < 8; ++j) o[j] = f2h(__expf(h2f(v[j]) - m));
        *(u16x8*)&Ep[rowi*EP_STRIDE + px8] = o;
      }
    }
    #pragma unroll
    for (int ps = 0; ps < 4; ++ps){
      int c = ps*64 + rr;
      const float* g = featB + (size_t)c*HW + p0 + px8;
      f32x4 v0 = *(const f32x4*)&g[0];
      f32x4 v1 = *(const f32x4*)&g[4];
      u16x8 o = {f2h(v0[0]), f2h(v0[1]), f2h(v0[2]), f2h(v0[3]),
                 f2h(v1[0]), f2h(v1[1]), f2h(v1[2]), f2h(v1[3])};
      *(u16x8*)&fN[c*FN_STRIDE + px8] = o;
    }
    __syncthreads();
    #pragma unroll
    for (int kb = 0; kb < 2; ++kb){
      int ko = kb*32 + lk*8;
      f16x8 a0 = *(const f16x8*)&fN[(cstrip + l15)*FN_STRIDE + ko];
      f16x8 a1 = *(const f16x8*)&fN[(cstrip + 16 + l15)*FN_STRIDE + ko];
      #pragma unroll
      for (int nf = 0; nf < 10; ++nf){
        f16x8 bb = *(const f16x8*)&Ep[(nf*16 + l15)*EP_STRIDE + ko];
        acc[0][nf] = MFMA16F(a0, bb, acc[0][nf], 0, 0, 0);
        acc[1][nf] = MFMA16F(a1, bb, acc[1][nf], 0, 0, 0);
      }
    }
    __syncthreads();
  }
  #pragma unroll
  for (int cf = 0; cf < 2; ++cf){
    #pragma unroll
    for (int nf = 0; nf < 10; ++nf){
      #pragma unroll
      for (int r = 0; r < 4; ++r){
        int c = cstrip + cf*16 + lk*4 + r;
        int n = nf*16 + l15;
        part[((size_t)(b*32 + pr)*CDIM + c)*NPAD + n] = f2h(acc[cf][nf][r]);
      }
    }
  }
}

// ---------------- k4a: streaming reduce of part over 32 chunks, fold rZ -> combT[b][n][c] f16
__global__ __launch_bounds__(256) void k4a(const u16* __restrict__ part, const float* __restrict__ rz,
                                           u16* __restrict__ combT){
  int b = blockIdx.x / 20, sub = blockIdx.x % 20, t = threadIdx.x;
  int idx8 = (sub*256 + t)*8;
  int c = idx8 / NPAD, n0 = idx8 % NPAD;
  const u16* base = part + (size_t)(b*32)*CDIM*NPAD + idx8;
  float a[8];
  #pragma unroll
  for (int j = 0; j < 8; ++j) a[j] = 0.f;
  for (int s = 0; s < 32; ++s){
    u16x8 v = *(const u16x8*)&base[(size_t)s*CDIM*NPAD];
    #pragma unroll
    for (int j = 0; j < 8; ++j) a[j] += h2f(v[j]);
  }
  const float* rzB = rz + b*NPAD + n0;
  #pragma unroll
  for (int j = 0; j < 8; ++j){
    combT[((size_t)(b*NPAD) + n0 + j)*CDIM + c] = f2h(a[j] * rzB[j]);
  }
}

// ---------------- k4b: out0[n][c] = cls + combT[n][:] @ WcF[c][:]  (MFMA, 80 n-rows/block)
__global__ __launch_bounds__(512) void k4b(const u16* __restrict__ combT, const u16* __restrict__ WcF,
                                           const float* __restrict__ cls, float* __restrict__ out0){
  extern __shared__ char sm[];
  u16* A = (u16*)sm;   // [80][CT_STRIDE]
  int b = blockIdx.x >> 1, nb = blockIdx.x & 1, t = threadIdx.x;
  const u16* cb = combT + (size_t)(b*NPAD + nb*80)*CDIM;
  #pragma unroll
  for (int it = 0; it < 10; ++it){
    int idx8 = (it*512 + t)*8;
    if (idx8 < 80*256){
      int row = idx8 >> 8, k0 = idx8 & 255;
      u16x8 v = *(const u16x8*)&cb[idx8];
      *(u16x8*)&A[row*CT_STRIDE + k0] = v;
    }
  }
  __syncthreads();
  int lane = t & 63, wv = t >> 6;
  int l15 = lane & 15, lk = (lane >> 4) & 3;
  int cstrip = wv*32;
  f32x4 acc[5][2];
  #pragma unroll
  for (int f = 0; f < 5; ++f)
    #pragma unroll
    for (int ct = 0; ct < 2; ++ct) acc[f][ct] = (f32x4){0.f,0.f,0.f,0.f};
  #pragma unroll
  for (int kb = 0; kb < 8; ++kb){
    int ko = kb*32 + lk*8;
    f16x8 b0 = *(const f16x8*)&WcF[(cstrip + l15)*CDIM + ko];
    f16x8 b1 = *(const f16x8*)&WcF[(cstrip + 16 + l15)*CDIM + ko];
    #pragma unroll
    for (int f = 0; f < 5; ++f){
      f16x8 af = *(const f16x8*)&A[(f*16 + l15)*CT_STRIDE + ko];
      acc[f][0] = MFMA16F(af, b0, acc[f][0], 0, 0, 0);
      acc[f][1] = MFMA16F(af, b1, acc[f][1], 0, 0, 0);
    }
  }
  #pragma unroll
  for (int f = 0; f < 5; ++f){
    #pragma unroll
    for (int r = 0; r < 4; ++r){
      int n = nb*80 + f*16 + lk*4 + r;
      if (n < NCLS){
        #pragma unroll
        for (int ct = 0; ct < 2; ++ct){
          int c = cstrip + ct*16 + l15;
          out0[(size_t)(b*NCLS + n)*CDIM + c] = cls[(size_t)(b*NCLS + n)*CDIM + c] + acc[f][ct][r];
        }
      }
    }
  }
}

extern "C" void kernel_launch(void* const* d_in, const int* in_sizes, int n_in,
                              void* d_out, int out_size, void* d_ws, size_t ws_size,
                              hipStream_t stream){
  (void)in_sizes; (void)n_in; (void)out_size; (void)ws_size;
  const float* cls  = (const float*)d_in[0];   // [8][150][256]
  const float* feat = (const float*)d_in[1];   // [8][256][16384]
  const float* Wc   = (const float*)d_in[2];   // [256][256]
  const float* Wf   = (const float*)d_in[3];   // [256][256]
  float* out0 = (float*)d_out;                 // [8][150][256]
  float* out1 = out0 + 8*NCLS*CDIM;            // [8][256][16384]
  char* ws = (char*)d_ws;
  u16*   clsF   = (u16*)(ws + WS_CLSF);
  u16*   clsWT  = (u16*)(ws + WS_CLSWT);
  float* mgv    = (float*)(ws + WS_MG);
  float* rzv    = (float*)(ws + WS_RZ);
  u16*   WcFv   = (u16*)(ws + WS_WCF);
  u16*   combTv = (u16*)(ws + WS_COMBT);
  float* rowPv  = (float*)(ws + WS_ROWP);
  u16*   partv  = (u16*)(ws + WS_PART);
  u16*   Sgp    = (u16*)(ws + WS_S);

  hipFuncSetAttribute((const void*)kS3,   hipFuncAttributeMaxDynamicSharedMemorySize, S3_LDS);
  hipFuncSetAttribute((const void*)kOut1, hipFuncAttributeMaxDynamicSharedMemorySize, O1_LDS);

  k0   <<<8*NPAD, 256, 0, stream>>>(cls, Wf, clsF, clsWT);
  kW   <<<32, 512, 0, stream>>>(Wc, WcFv);
  kS3  <<<512, 256, S3_LDS, stream>>>(feat, clsF, Sgp, rowPv);
  kComb<<<8, 256, 0, stream>>>(rowPv, mgv, rzv);
  kOut1<<<256, 512, O1_LDS, stream>>>(Sgp, clsWT, feat, out1);
  kOut0<<<256, 512, (NPAD*EP_STRIDE + CDIM*FN_STRIDE)*2, stream>>>(Sgp, feat, mgv, partv);
  k4a  <<<160, 256, 0, stream>>>(partv, rzv, combTv);
  k4b  <<<16, 512, 80*CT_STRIDE*2, stream>>>(combTv, WcFv, cls, out0);
}

// Round 11
// 223.174 us; speedup vs baseline: 1.3008x; 1.3008x over previous
//
#include <hip/hip_runtime.h>

typedef unsigned short u16;
typedef __attribute__((ext_vector_type(8))) _Float16 f16x8;
typedef __attribute__((ext_vector_type(4))) float f32x4;
typedef __attribute__((ext_vector_type(4))) unsigned short u16x4;
typedef __attribute__((ext_vector_type(8))) unsigned short u16x8;

#define MFMA16F __builtin_amdgcn_mfma_f32_16x16x32_f16

#define HW   16384
#define NCLS 150
#define NPAD 160
#define CDIM 256

// LDS strides (shorts)
#define FT_STRIDE 264   // featT [64 px][256 c]
#define KC_STRIDE 72    // clsK  [160 n][64 c]
#define FN_STRIDE 72    // featN [256 c][64 px]
#define EP_STRIDE 72    // E'    [160 n][64 px]
#define W_STRIDE  168   // E [64 px][160 n]; clsWT rows
#define CT_STRIDE 264   // combT tile [80 n][256 k]

// kSO1 LDS layout (bytes): 64512 -> 2 blocks/CU
#define SO_FT   0        // [64][264] u16 = 33792
#define SO_CK   33792    // clsK [160][72] u16 = 23040; E [64][168] u16 = 21504 aliases
#define SO_ROWM 56832    // [160][4] f32 = 2560
#define SO_ROWS 59392    // [160][4] f32 = 2560
#define SO_MP   61952    // [64] f32 = 256
#define SO_PS   62208    // [64][8] f32 = 2048
#define SO_RZ   64256    // [64] f32 = 256
#define SO_LDS  64512

// workspace offsets (bytes)
#define WS_CLSF  0          // [8][160][256] f16
#define WS_CLSWT 655360     // [8][256][160] f16
#define WS_MG    2359296    // [8][160] f32
#define WS_RZ    2364416    // [8][160] f32
#define WS_WCF   2369536    // [256][256] f16
#define WS_COMBT 2500608    // [8][160][256] f16
#define WS_ROWP  3155968    // [8][256][160][2] f32 = 2,621,440 (part aliases after kComb)
#define WS_PART  3155968    // [8][32][256][160] f16 (written later by kOut0)
#define WS_S     24127488   // [8][160][16384] f16

__device__ __forceinline__ u16 f2h(float f){ return __builtin_bit_cast(u16, (_Float16)f); }
__device__ __forceinline__ float h2f(u16 h){ return (float)__builtin_bit_cast(_Float16, h); }

// ---------------- k0: cls -> f16 (padded 160 rows, pads zero), clsWT = (cls @ Wf^T)^T f16
__global__ __launch_bounds__(256) void k0(const float* __restrict__ cls, const float* __restrict__ Wf,
                                          u16* __restrict__ clsF, u16* __restrict__ clsWT){
  int b = blockIdx.x / NPAD, n = blockIdx.x % NPAD, t = threadIdx.x;
  __shared__ float row[256];
  int bn = b*NPAD + n;
  if (n < NCLS){
    float v = cls[(b*NCLS + n)*CDIM + t];
    clsF[bn*CDIM + t] = f2h(v);
    row[t] = v;
    __syncthreads();
    float acc = 0.f;
    const float* wr = Wf + t*CDIM;
    #pragma unroll 4
    for (int c = 0; c < 256; c += 4){
      acc += row[c]*wr[c] + row[c+1]*wr[c+1] + row[c+2]*wr[c+2] + row[c+3]*wr[c+3];
    }
    clsWT[(b*CDIM + t)*NPAD + n] = f2h(acc);
  } else {
    clsF[bn*CDIM + t] = 0;
    clsWT[(b*CDIM + t)*NPAD + n] = 0;
  }
}

// ---------------- kW: Wc f32 -> f16
__global__ __launch_bounds__(512) void kW(const float* __restrict__ Wc, u16* __restrict__ WcF){
  int i = (blockIdx.x*512 + threadIdx.x)*4;
  f32x4 v = *(const f32x4*)&Wc[i];
  u16x4 o = {f2h(v[0]), f2h(v[1]), f2h(v[2]), f2h(v[3])};
  *(u16x4*)&WcF[i] = o;
}

// ---------------- kSO1: fused S-GEMM (K-chunked LDS cls) + row stats + local pixel softmax
//                  + out1-GEMM. One (b, 64px tile) per block; 2 blocks/CU.
__global__ __launch_bounds__(512) void kSO1(const float* __restrict__ feat,
                                            const u16* __restrict__ clsF,
                                            const u16* __restrict__ clsWT,
                                            u16* __restrict__ Sg, float* __restrict__ rowP,
                                            float* __restrict__ out1){
  extern __shared__ char sm[];
  u16*  ftF  = (u16*)(sm + SO_FT);
  u16*  clsK = (u16*)(sm + SO_CK);
  u16*  E    = (u16*)(sm + SO_CK);     // alias: clsK dead after S-GEMM
  float* rowM = (float*)(sm + SO_ROWM);
  float* rowS = (float*)(sm + SO_ROWS);
  float* mpL  = (float*)(sm + SO_MP);
  float* psum = (float*)(sm + SO_PS);
  float* rzL  = (float*)(sm + SO_RZ);

  int b = blockIdx.x & 7, tl = blockIdx.x >> 3, t = threadIdx.x;
  int p0 = tl*64;
  const float* featG = feat + (size_t)b*CDIM*HW;
  const u16* clsB  = clsF  + b*NPAD*CDIM;
  const u16* clsWB = clsWT + b*CDIM*NPAD;
  u16* Sb = Sg + (size_t)b*NPAD*HW;

  int lane = t & 63, wv = t >> 6;
  int l15 = lane & 15, lk = (lane >> 4) & 3;
  int nh = wv >> 2, pq = wv & 3;
  int nbase = nh*80;
  int col = pq*16 + l15;
  int cstrip = wv*32;

  // ---- stage ftF [64px][256c] f32->f16 (once)
  {
    int p = t & 63, cg = t >> 6;
    #pragma unroll
    for (int i = 0; i < 8; ++i){
      int c0 = (i*8 + cg)*4;
      const float* g0 = featG + (size_t)c0*HW + p0 + p;
      float v0 = g0[0], v1 = g0[HW], v2 = g0[2*HW], v3 = g0[3*HW];
      u16x4 hv = {f2h(v0), f2h(v1), f2h(v2), f2h(v3)};
      *(u16x4*)&ftF[p*FT_STRIDE + c0] = hv;
    }
  }
  // ---- S-GEMM: K-loop, cls chunk staged to LDS (coalesced, parallel — no serial frag loads)
  f32x4 acc[5];
  #pragma unroll
  for (int f = 0; f < 5; ++f) acc[f] = (f32x4){0.f,0.f,0.f,0.f};
  for (int kc = 0; kc < 4; ++kc){
    #pragma unroll
    for (int it = 0; it < 3; ++it){
      int idx = it*512 + t;
      if (idx < 1280){
        int n = idx >> 3, s8 = idx & 7;
        u16x8 v = *(const u16x8*)&clsB[n*CDIM + kc*64 + s8*8];
        *(u16x8*)&clsK[n*KC_STRIDE + s8*8] = v;
      }
    }
    __syncthreads();   // clsK (and on kc=0, ftF) ready
    #pragma unroll
    for (int kb2 = 0; kb2 < 2; ++kb2){
      int kol = kb2*32 + lk*8;
      f16x8 bh = *(const f16x8*)&ftF[(pq*16 + l15)*FT_STRIDE + kc*64 + kol];
      #pragma unroll
      for (int f = 0; f < 5; ++f){
        f16x8 ah = *(const f16x8*)&clsK[(nbase + f*16 + l15)*KC_STRIDE + kol];
        acc[f] = MFMA16F(ah, bh, acc[f], 0, 0, 0);
      }
    }
    __syncthreads();   // clsK reads done before next-stage overwrite
  }
  // ---- preload clsWT fragments early (latency hides under stats/softmax phases)
  f16x8 aw0[5], aw1[5];
  #pragma unroll
  for (int kb = 0; kb < 5; ++kb){
    aw0[kb] = *(const f16x8*)&clsWB[(cstrip + l15)*NPAD + kb*32 + lk*8];
    aw1[kb] = *(const f16x8*)&clsWB[(cstrip + 16 + l15)*NPAD + kb*32 + lk*8];
  }
  #pragma unroll
  for (int kb = 0; kb < 5; ++kb){
    asm volatile("" :: "v"(aw0[kb]), "v"(aw1[kb]));
  }
  // ---- write S to global (for kOut0)
  #pragma unroll
  for (int f = 0; f < 5; ++f){
    #pragma unroll
    for (int r = 0; r < 4; ++r){
      int n = nbase + f*16 + 4*lk + r;
      Sb[(size_t)n*HW + p0 + col] = f2h(acc[f][r]);
    }
  }
  // ---- row (cls) stats: shfl-reduce (m,s) over this wave's 16 cols
  #pragma unroll
  for (int f = 0; f < 5; ++f){
    #pragma unroll
    for (int r = 0; r < 4; ++r){
      float v = acc[f][r];
      float m = v;
      m = fmaxf(m, __shfl_xor(m, 1));
      m = fmaxf(m, __shfl_xor(m, 2));
      m = fmaxf(m, __shfl_xor(m, 4));
      m = fmaxf(m, __shfl_xor(m, 8));
      float s = __expf(v - m);
      s += __shfl_xor(s, 1);
      s += __shfl_xor(s, 2);
      s += __shfl_xor(s, 4);
      s += __shfl_xor(s, 8);
      if (l15 == f){
        int n = nbase + f*16 + 4*lk + r;
        rowM[n*4 + pq] = m;
        rowS[n*4 + pq] = s;
      }
    }
  }
  // ---- write raw S^T into E (u16x4 per fragment; pads n>=150 handled in P3)
  #pragma unroll
  for (int f = 0; f < 5; ++f){
    u16x4 ev = {f2h(acc[f][0]), f2h(acc[f][1]), f2h(acc[f][2]), f2h(acc[f][3])};
    *(u16x4*)&E[col*W_STRIDE + nbase + f*16 + 4*lk] = ev;
  }
  __syncthreads();   // E raw + rowM/rowS ready
  // ---- combine row stats -> rowP; per-pixel max (contiguous scans)
  if (t < NPAD){
    float rm0 = rowM[t*4+0], rm1 = rowM[t*4+1], rm2 = rowM[t*4+2], rm3 = rowM[t*4+3];
    float msub = fmaxf(fmaxf(rm0, rm1), fmaxf(rm2, rm3));
    float l = rowS[t*4+0]*__expf(rm0 - msub) + rowS[t*4+1]*__expf(rm1 - msub)
            + rowS[t*4+2]*__expf(rm2 - msub) + rowS[t*4+3]*__expf(rm3 - msub);
    float* rp = rowP + ((size_t)(b*256 + tl)*NPAD + t)*2;
    rp[0] = msub;
    rp[1] = l;
  }
  if (t < 64){
    float mt = -3.0e38f;
    #pragma unroll
    for (int q = 0; q < 18; ++q){
      u16x8 v = *(const u16x8*)&E[t*W_STRIDE + q*8];
      #pragma unroll
      for (int j = 0; j < 8; ++j) mt = fmaxf(mt, h2f(v[j]));
    }
    for (int n = 144; n < NCLS; ++n) mt = fmaxf(mt, h2f(E[t*W_STRIDE + n]));
    mpL[t] = mt;
  }
  __syncthreads();   // mpL ready
  // ---- P3: raw->exp in place (512 threads), partial sums, zero pads
  {
    int px = t >> 3, sl = t & 7;
    float mt = mpL[px];
    float s = 0.f;
    int n0 = sl*21;
    for (int n = n0; n < n0 + 21; ++n){
      float e = 0.f;
      if (n < NCLS){ e = __expf(h2f(E[px*W_STRIDE + n]) - mt); s += e; }
      if (n < NPAD) E[px*W_STRIDE + n] = f2h(e);
    }
    psum[px*8 + sl] = s;
  }
  __syncthreads();   // E(exp) + psum ready
  // ---- rz (t<64) concurrent with out1-GEMM
  if (t < 64){
    float z = 0.f;
    #pragma unroll
    for (int j = 0; j < 8; ++j) z += psum[t*8 + j];
    rzL[t] = 1.0f / z;
  }
  f32x4 accO[2][4];
  #pragma unroll
  for (int cf = 0; cf < 2; ++cf)
    #pragma unroll
    for (int pf = 0; pf < 4; ++pf) accO[cf][pf] = (f32x4){0.f,0.f,0.f,0.f};
  #pragma unroll
  for (int kb = 0; kb < 5; ++kb){
    int ko = kb*32 + lk*8;
    #pragma unroll
    for (int pf = 0; pf < 4; ++pf){
      f16x8 bb = *(const f16x8*)&E[(pf*16 + l15)*W_STRIDE + ko];
      accO[0][pf] = MFMA16F(aw0[kb], bb, accO[0][pf], 0, 0, 0);
      accO[1][pf] = MFMA16F(aw1[kb], bb, accO[1][pf], 0, 0, 0);
    }
  }
  __syncthreads();   // rzL visible
  // ---- epilogue: scale by 1/Z, add f16 feat residual from ftF
  #pragma unroll
  for (int cf = 0; cf < 2; ++cf){
    #pragma unroll
    for (int r = 0; r < 4; ++r){
      int c = cstrip + cf*16 + lk*4 + r;
      float* ob = out1 + (size_t)(b*CDIM + c)*HW + p0;
      #pragma unroll
      for (int pf = 0; pf < 4; ++pf){
        int pp = pf*16 + l15;
        ob[pp] = accO[cf][pf][r]*rzL[pp] + h2f(ftF[pp*FT_STRIDE + c]);
      }
    }
  }
}

// ---------------- kComb: reduce 256 tile row-partials -> m_g, rZ (2-level)
__global__ __launch_bounds__(256) void kComb(const float* __restrict__ rowP,
                                             float* __restrict__ mg, float* __restrict__ rz){
  int b = blockIdx.x / 10, nb = blockIdx.x % 10, t = threadIdx.x;
  int sg = t >> 4, j = t & 15;
  int n = nb*16 + j;
  __shared__ float pm[16][17], pl[16][17];
  float m = -3.0e38f, l = 0.f;
  for (int i = 0; i < 16; ++i){
    int s = sg*16 + i;
    const float* rp = rowP + ((size_t)(b*256 + s)*NPAD + n)*2;
    float ms = rp[0], ls = rp[1];
    float mn = fmaxf(m, ms);
    l = l*__expf(m - mn) + ls*__expf(ms - mn);
    m = mn;
  }
  pm[sg][j] = m;
  pl[sg][j] = l;
  __syncthreads();
  if (sg == 0){
    float M = pm[0][j], L = pl[0][j];
    #pragma unroll
    for (int k = 1; k < 16; ++k){
      float ms = pm[k][j], ls = pl[k][j];
      float mn = fmaxf(M, ms);
      L = L*__expf(M - mn) + ls*__expf(ms - mn);
      M = mn;
    }
    mg[b*NPAD + n] = M;
    rz[b*NPAD + n] = 1.0f / L;
  }
}

// ---------------- kOut0: part[c][n] = sum_p featF16[c][p] * exp(S - m_g[n])  (512 px/block)
__global__ __launch_bounds__(512) void kOut0(const u16* __restrict__ Sg, const float* __restrict__ feat,
                                             const float* __restrict__ mg, u16* __restrict__ part){
  extern __shared__ char sm[];
  u16* Ep = (u16*)sm;                        // [NPAD][EP_STRIDE]
  u16* fN = (u16*)(sm + NPAD*EP_STRIDE*2);   // [CDIM][FN_STRIDE]
  int b = blockIdx.x & 7, pr = blockIdx.x >> 3, t = threadIdx.x;
  const u16* Sb = Sg + (size_t)b*NPAD*HW;
  const float* featB = feat + (size_t)b*CDIM*HW;
  const float* mgB = mg + b*NPAD;
  int lane = t & 63, wv = t >> 6;
  int l15 = lane & 15, lk = (lane >> 4) & 3;
  int cstrip = wv*32;
  int rr = t >> 3, px8 = (t & 7)*8;
  f32x4 acc[2][10];
  #pragma unroll
  for (int cf = 0; cf < 2; ++cf)
    #pragma unroll
    for (int nf = 0; nf < 10; ++nf) acc[cf][nf] = (f32x4){0.f,0.f,0.f,0.f};
  for (int ck = 0; ck < 8; ++ck){
    int p0 = pr*512 + ck*64;
    #pragma unroll
    for (int ps = 0; ps < 3; ++ps){
      int rowi = ps*64 + rr;
      if (rowi < NPAD){
        u16x8 v = *(const u16x8*)&Sb[(size_t)rowi*HW + p0 + px8];
        float m = mgB[rowi];
        u16x8 o;
        #pragma unroll
        for (int j = 0; j < 8; ++j) o[j] = f2h(__expf(h2f(v[j]) - m));
        *(u16x8*)&Ep[rowi*EP_STRIDE + px8] = o;
      }
    }
    #pragma unroll
    for (int ps = 0; ps < 4; ++ps){
      int c = ps*64 + rr;
      const float* g = featB + (size_t)c*HW + p0 + px8;
      f32x4 v0 = *(const f32x4*)&g[0];
      f32x4 v1 = *(const f32x4*)&g[4];
      u16x8 o = {f2h(v0[0]), f2h(v0[1]), f2h(v0[2]), f2h(v0[3]),
                 f2h(v1[0]), f2h(v1[1]), f2h(v1[2]), f2h(v1[3])};
      *(u16x8*)&fN[c*FN_STRIDE + px8] = o;
    }
    __syncthreads();
    #pragma unroll
    for (int kb = 0; kb < 2; ++kb){
      int ko = kb*32 + lk*8;
      f16x8 a0 = *(const f16x8*)&fN[(cstrip + l15)*FN_STRIDE + ko];
      f16x8 a1 = *(const f16x8*)&fN[(cstrip + 16 + l15)*FN_STRIDE + ko];
      #pragma unroll
      for (int nf = 0; nf < 10; ++nf){
        f16x8 bb = *(const f16x8*)&Ep[(nf*16 + l15)*EP_STRIDE + ko];
        acc[0][nf] = MFMA16F(a0, bb, acc[0][nf], 0, 0, 0);
        acc[1][nf] = MFMA16F(a1, bb, acc[1][nf], 0, 0, 0);
      }
    }
    __syncthreads();
  }
  #pragma unroll
  for (int cf = 0; cf < 2; ++cf){
    #pragma unroll
    for (int nf = 0; nf < 10; ++nf){
      #pragma unroll
      for (int r = 0; r < 4; ++r){
        int c = cstrip + cf*16 + lk*4 + r;
        int n = nf*16 + l15;
        part[((size_t)(b*32 + pr)*CDIM + c)*NPAD + n] = f2h(acc[cf][nf][r]);
      }
    }
  }
}

// ---------------- k4a: streaming reduce of part over 32 chunks, fold rZ -> combT[b][n][c] f16
__global__ __launch_bounds__(256) void k4a(const u16* __restrict__ part, const float* __restrict__ rz,
                                           u16* __restrict__ combT){
  int b = blockIdx.x / 20, sub = blockIdx.x % 20, t = threadIdx.x;
  int idx8 = (sub*256 + t)*8;
  int c = idx8 / NPAD, n0 = idx8 % NPAD;
  const u16* base = part + (size_t)(b*32)*CDIM*NPAD + idx8;
  float a[8];
  #pragma unroll
  for (int j = 0; j < 8; ++j) a[j] = 0.f;
  for (int s = 0; s < 32; ++s){
    u16x8 v = *(const u16x8*)&base[(size_t)s*CDIM*NPAD];
    #pragma unroll
    for (int j = 0; j < 8; ++j) a[j] += h2f(v[j]);
  }
  const float* rzB = rz + b*NPAD + n0;
  #pragma unroll
  for (int j = 0; j < 8; ++j){
    combT[((size_t)(b*NPAD) + n0 + j)*CDIM + c] = f2h(a[j] * rzB[j]);
  }
}

// ---------------- k4b: out0[n][c] = cls + combT[n][:] @ WcF[c][:]  (MFMA, 80 n-rows/block)
__global__ __launch_bounds__(512) void k4b(const u16* __restrict__ combT, const u16* __restrict__ WcF,
                                           const float* __restrict__ cls, float* __restrict__ out0){
  extern __shared__ char sm[];
  u16* A = (u16*)sm;   // [80][CT_STRIDE]
  int b = blockIdx.x >> 1, nb = blockIdx.x & 1, t = threadIdx.x;
  const u16* cb = combT + (size_t)(b*NPAD + nb*80)*CDIM;
  #pragma unroll
  for (int it = 0; it < 10; ++it){
    int idx8 = (it*512 + t)*8;
    if (idx8 < 80*256){
      int row = idx8 >> 8, k0 = idx8 & 255;
      u16x8 v = *(const u16x8*)&cb[idx8];
      *(u16x8*)&A[row*CT_STRIDE + k0] = v;
    }
  }
  __syncthreads();
  int lane = t & 63, wv = t >> 6;
  int l15 = lane & 15, lk = (lane >> 4) & 3;
  int cstrip = wv*32;
  f32x4 acc[5][2];
  #pragma unroll
  for (int f = 0; f < 5; ++f)
    #pragma unroll
    for (int ct = 0; ct < 2; ++ct) acc[f][ct] = (f32x4){0.f,0.f,0.f,0.f};
  #pragma unroll
  for (int kb = 0; kb < 8; ++kb){
    int ko = kb*32 + lk*8;
    f16x8 b0 = *(const f16x8*)&WcF[(cstrip + l15)*CDIM + ko];
    f16x8 b1 = *(const f16x8*)&WcF[(cstrip + 16 + l15)*CDIM + ko];
    #pragma unroll
    for (int f = 0; f < 5; ++f){
      f16x8 af = *(const f16x8*)&A[(f*16 + l15)*CT_STRIDE + ko];
      acc[f][0] = MFMA16F(af, b0, acc[f][0], 0, 0, 0);
      acc[f][1] = MFMA16F(af, b1, acc[f][1], 0, 0, 0);
    }
  }
  #pragma unroll
  for (int f = 0; f < 5; ++f){
    #pragma unroll
    for (int r = 0; r < 4; ++r){
      int n = nb*80 + f*16 + lk*4 + r;
      if (n < NCLS){
        #pragma unroll
        for (int ct = 0; ct < 2; ++ct){
          int c = cstrip + ct*16 + l15;
          out0[(size_t)(b*NCLS + n)*CDIM + c] = cls[(size_t)(b*NCLS + n)*CDIM + c] + acc[f][ct][r];
        }
      }
    }
  }
}

extern "C" void kernel_launch(void* const* d_in, const int* in_sizes, int n_in,
                              void* d_out, int out_size, void* d_ws, size_t ws_size,
                              hipStream_t stream){
  (void)in_sizes; (void)n_in; (void)out_size; (void)ws_size;
  const float* cls  = (const float*)d_in[0];   // [8][150][256]
  const float* feat = (const float*)d_in[1];   // [8][256][16384]
  const float* Wc   = (const float*)d_in[2];   // [256][256]
  const float* Wf   = (const float*)d_in[3];   // [256][256]
  float* out0 = (float*)d_out;                 // [8][150][256]
  float* out1 = out0 + 8*NCLS*CDIM;            // [8][256][16384]
  char* ws = (char*)d_ws;
  u16*   clsF   = (u16*)(ws + WS_CLSF);
  u16*   clsWT  = (u16*)(ws + WS_CLSWT);
  float* mgv    = (float*)(ws + WS_MG);
  float* rzv    = (float*)(ws + WS_RZ);
  u16*   WcFv   = (u16*)(ws + WS_WCF);
  u16*   combTv = (u16*)(ws + WS_COMBT);
  float* rowPv  = (float*)(ws + WS_ROWP);
  u16*   partv  = (u16*)(ws + WS_PART);
  u16*   Sgp    = (u16*)(ws + WS_S);

  hipFuncSetAttribute((const void*)kSO1, hipFuncAttributeMaxDynamicSharedMemorySize, SO_LDS);

  k0   <<<8*NPAD, 256, 0, stream>>>(cls, Wf, clsF, clsWT);
  kW   <<<32, 512, 0, stream>>>(Wc, WcFv);
  kSO1 <<<2048, 512, SO_LDS, stream>>>(feat, clsF, clsWT, Sgp, rowPv, out1);
  kComb<<<80, 256, 0, stream>>>(rowPv, mgv, rzv);
  kOut0<<<256, 512, (NPAD*EP_STRIDE + CDIM*FN_STRIDE)*2, stream>>>(Sgp, feat, mgv, partv);
  k4a  <<<160, 256, 0, stream>>>(partv, rzv, combTv);
  k4b  <<<16, 512, 80*CT_STRIDE*2, stream>>>(combTv, WcFv, cls, out0);
}